// Round 4
// baseline (1451.356 us; speedup 1.0000x reference)
//
#include <hip/hip_runtime.h>
#include <hip/hip_bf16.h>
#include <cstdint>

#define NN   100000
#define TT   4
#define EE   250000
#define LL   2
#define NCH  49            // ceil(NN/2048)
#define EPN  (EE + NN)     // 350000

static __device__ __forceinline__ float gelu_exact(float v) {
    return 0.5f * v * (1.0f + erff(v * 0.7071067811865476f));
}
static __device__ __forceinline__ float wave_sum64(float v) {
    #pragma unroll
    for (int m = 32; m; m >>= 1) v += __shfl_xor(v, m, 64);
    return v;
}

// ---------------------------------------------------------------------------
// Prep: collapsed logit weights w_coll[l][d][col] (col = t*8 + side*4 + h),
// projection Bproj[(l*1024 + t*256 + h*64 + d)*64 + c] = 0.25*W_src[l,t,d,h*64+c]
// (t-major so 4 types concatenate into one K=1024 GEMM),
// bias_sum[l][c] = sum_t conv_bias[l,t,c].
// ---------------------------------------------------------------------------
__global__ __launch_bounds__(256) void k_prep(
    const float* __restrict__ Wsrc, const float* __restrict__ Wdst,
    const float* __restrict__ asrc, const float* __restrict__ adst,
    const float* __restrict__ cb,
    float* __restrict__ wcoll, float* __restrict__ bproj, float* __restrict__ bsum)
{
    int id = blockIdx.x * 256 + threadIdx.x;   // grid = 131072 exactly
    {   // Bproj: id = ((l*1024 + t*256 + h*64 + d)*64 + c)
        int c = id & 63;
        int d = (id >> 6) & 63;
        int h = (id >> 12) & 3;
        int t = (id >> 14) & 3;
        int l = (id >> 16) & 1;
        bproj[id] = 0.25f * Wsrc[(((l * 4 + t) * 64 + d) * 256) + h * 64 + c];
    }
    if (id < LL * 64 * 64) {   // w_coll
        int col = id & 63;
        int d   = (id >> 6) & 63;
        int l   = id >> 12;
        int t = col >> 3, side = (col >> 2) & 1, h = col & 3;
        const float* W = side ? Wdst : Wsrc;
        const float* a = side ? adst : asrc;
        int wb = ((l * 4 + t) * 64 + d) * 256 + h * 64;
        int ab = ((l * 4 + t) * 4 + h) * 64;
        float s = 0.f;
        #pragma unroll 8
        for (int c2 = 0; c2 < 64; ++c2) s = fmaf(W[wb + c2], a[ab + c2], s);
        wcoll[id] = s;
    }
    if (id < LL * 64) {        // bias_sum
        int l = id >> 6, c = id & 63;
        float s = 0.f;
        for (int t = 0; t < TT; ++t) s += cb[(l * 4 + t) * 64 + c];
        bsum[id] = s;
    }
}

// ---------------------------------------------------------------------------
// CSR build (unchanged, verified)
// ---------------------------------------------------------------------------
__global__ void k_hist(const int* __restrict__ ei, int* __restrict__ cursor) {
    int id = blockIdx.x * 256 + threadIdx.x;
    if (id >= TT * EE) return;
    int t = id / EE, e = id - t * EE;
    int d = ei[(t * 2 + 1) * EE + e];
    atomicAdd(&cursor[t * NN + d], 1);
}

__global__ __launch_bounds__(256) void k_scan1(const int* __restrict__ deg,
                                               int* __restrict__ csum) {
    int b = blockIdx.x, t = b / NCH, cc = b - t * NCH;
    int tid = threadIdx.x;
    int base = cc * 2048 + tid * 8;
    int s = 0;
    #pragma unroll
    for (int i = 0; i < 8; ++i) {
        int idx = base + i;
        if (idx < NN) s += deg[t * NN + idx] + 1;   // +1: self loop
    }
    #pragma unroll
    for (int m = 32; m; m >>= 1) s += __shfl_xor(s, m, 64);
    __shared__ int ws4[4];
    int lane = tid & 63, wid = tid >> 6;
    if (lane == 0) ws4[wid] = s;
    __syncthreads();
    if (tid == 0) csum[b] = ws4[0] + ws4[1] + ws4[2] + ws4[3];
}

__global__ void k_scan2(const int* __restrict__ csum, int* __restrict__ cbase,
                        int* __restrict__ row_ptr) {
    int t = threadIdx.x;
    if (t >= TT) return;
    int base = 0;
    for (int c = 0; c < NCH; ++c) {
        cbase[t * NCH + c] = base;
        base += csum[t * NCH + c];
    }
    row_ptr[t * (NN + 1) + NN] = base;   // = EE + NN
}

__global__ __launch_bounds__(256) void k_scan3(int* __restrict__ cursor,
                                               const int* __restrict__ cbase,
                                               int* __restrict__ row_ptr) {
    int b = blockIdx.x, t = b / NCH, cc = b - t * NCH;
    int tid = threadIdx.x, lane = tid & 63, wid = tid >> 6;
    int base = cc * 2048 + tid * 8;
    int vals[8], ts = 0;
    #pragma unroll
    for (int i = 0; i < 8; ++i) {
        int idx = base + i;
        int v = (idx < NN) ? cursor[t * NN + idx] + 1 : 0;
        vals[i] = v; ts += v;
    }
    int v = ts;
    #pragma unroll
    for (int off = 1; off < 64; off <<= 1) {
        int u = __shfl_up(v, off, 64);
        if (lane >= off) v += u;
    }
    __shared__ int wt[4];
    if (lane == 63) wt[wid] = v;
    __syncthreads();
    int wbase = 0;
    for (int w = 0; w < wid; ++w) wbase += wt[w];
    int run = cbase[t * NCH + cc] + wbase + (v - ts);
    #pragma unroll
    for (int i = 0; i < 8; ++i) {
        int idx = base + i;
        if (idx < NN) {
            row_ptr[t * (NN + 1) + idx] = run;
            cursor[t * NN + idx] = run;     // becomes scatter write-head
        }
        run += vals[i];
    }
}

__global__ void k_scatter(const int* __restrict__ ei, int* __restrict__ cursor,
                          int* __restrict__ col) {
    int id = blockIdx.x * 256 + threadIdx.x;
    if (id >= TT * EPN) return;
    int t = id / EPN, r = id - t * EPN;
    int s, d;
    if (r < EE) { s = ei[t * 2 * EE + r]; d = ei[(t * 2 + 1) * EE + r]; }
    else        { s = d = r - EE; }
    int pos = atomicAdd(&cursor[t * NN + d], 1);
    col[(size_t)t * EPN + pos] = s;
}

// ---------------------------------------------------------------------------
// Tiled GEMM, runtime K: C[N,64] = A[N,K] @ B[K,64], fused epilogue.
// MODE bit0: read/accumulate Cin.  MODE bit1: final epilogue
//            gelu((v + bias) * 0.25)  (HeteroConv mean + head-mean-in-B + act)
// 128-thread blocks, 128-row tiles, 8x8 register tile per thread:
//   4 ds_read_b128 per 64 FMA -> halved LDS:VALU pressure vs round 2.
// ---------------------------------------------------------------------------
template <int MODE>
__global__ __launch_bounds__(128, 3) void k_gemm_rt(
    const float* __restrict__ A, const float* __restrict__ B,
    const float* __restrict__ Cin, float* __restrict__ Cout,
    const float* __restrict__ bias, int K, int nrows)
{
    constexpr int KC = 32, RT = 128, LDA = RT + 4;  // LDA=132 floats (33 f4)
    __shared__ float sA[KC * LDA];   // 16.9 KB
    __shared__ float sB[KC * 64];    // 8 KB
    const int tid = threadIdx.x;               // 0..127
    const int rowbase = blockIdx.x * RT;
    const int jc = tid & 7;                    // cols jc*8 .. jc*8+7
    const int rg = tid >> 3;                   // rows rg*8 .. rg*8+7 (0..15)
    const float4* sA4 = (const float4*)sA;
    const float4* sB4 = (const float4*)sB;

    float acc[8][8];
    #pragma unroll
    for (int i = 0; i < 8; ++i)
        #pragma unroll
        for (int j = 0; j < 8; ++j) acc[i][j] = 0.f;

    for (int kc = 0; kc < K; kc += KC) {
        __syncthreads();   // previous compute done before overwrite
        // stage B chunk: 32x64 floats = 512 float4, linear, conflict-free
        {
            const float4* Bg = (const float4*)(B + (size_t)kc * 64);
            float4* sBw = (float4*)sB;
            #pragma unroll
            for (int i = 0; i < 4; ++i) sBw[tid + i * 128] = Bg[tid + i * 128];
        }
        // stage A chunk: 128 rows x 32 cols, coalesced b128, transposed
        #pragma unroll
        for (int i = 0; i < 8; ++i) {
            int f = tid + i * 128;     // 0..1023
            int r = f >> 3;            // 0..127
            int cg = f & 7;            // float4 within 32-col chunk
            int row = rowbase + r;
            float4 v = (row < nrows)
                ? *(const float4*)(A + (size_t)row * K + kc + cg * 4)
                : make_float4(0.f, 0.f, 0.f, 0.f);
            int b0 = (cg * 4) * LDA + r;
            sA[b0]           = v.x;
            sA[b0 + LDA]     = v.y;
            sA[b0 + 2 * LDA] = v.z;
            sA[b0 + 3 * LDA] = v.w;
        }
        __syncthreads();
        #pragma unroll 8
        for (int k = 0; k < KC; ++k) {
            float4 a0 = sA4[k * 33 + rg * 2];
            float4 a1 = sA4[k * 33 + rg * 2 + 1];
            float4 b0 = sB4[k * 16 + jc * 2];
            float4 b1 = sB4[k * 16 + jc * 2 + 1];
            float av[8] = {a0.x, a0.y, a0.z, a0.w, a1.x, a1.y, a1.z, a1.w};
            float bv[8] = {b0.x, b0.y, b0.z, b0.w, b1.x, b1.y, b1.z, b1.w};
            #pragma unroll
            for (int i = 0; i < 8; ++i)
                #pragma unroll
                for (int j = 0; j < 8; ++j)
                    acc[i][j] = fmaf(av[i], bv[j], acc[i][j]);
        }
    }
    float4 bv0 = make_float4(0.f, 0.f, 0.f, 0.f), bv1 = bv0;
    if (MODE & 2) {
        bv0 = *(const float4*)(bias + jc * 8);
        bv1 = *(const float4*)(bias + jc * 8 + 4);
    }
    #pragma unroll
    for (int i = 0; i < 8; ++i) {
        int row = rowbase + rg * 8 + i;
        if (row < nrows) {
            size_t coff = (size_t)row * 64 + jc * 8;
            float4 r0, r1;
            r0.x = acc[i][0]; r0.y = acc[i][1]; r0.z = acc[i][2]; r0.w = acc[i][3];
            r1.x = acc[i][4]; r1.y = acc[i][5]; r1.z = acc[i][6]; r1.w = acc[i][7];
            if (MODE & 1) {
                float4 c0 = *(const float4*)(Cin + coff);
                float4 c1 = *(const float4*)(Cin + coff + 4);
                r0.x += c0.x; r0.y += c0.y; r0.z += c0.z; r0.w += c0.w;
                r1.x += c1.x; r1.y += c1.y; r1.z += c1.z; r1.w += c1.w;
            }
            if (MODE & 2) {
                r0.x = gelu_exact((r0.x + bv0.x) * 0.25f);
                r0.y = gelu_exact((r0.y + bv0.y) * 0.25f);
                r0.z = gelu_exact((r0.z + bv0.z) * 0.25f);
                r0.w = gelu_exact((r0.w + bv0.w) * 0.25f);
                r1.x = gelu_exact((r1.x + bv1.x) * 0.25f);
                r1.y = gelu_exact((r1.y + bv1.y) * 0.25f);
                r1.z = gelu_exact((r1.z + bv1.z) * 0.25f);
                r1.w = gelu_exact((r1.w + bv1.w) * 0.25f);
            }
            *(float4*)(Cout + coff) = r0;
            *(float4*)(Cout + coff + 4) = r1;
        }
    }
}

// ---------------------------------------------------------------------------
// Feature epilogue: x = gelu(LN(y + lin_b)) + l2norm(emb).  One wave per row.
// ---------------------------------------------------------------------------
__global__ __launch_bounds__(256) void k_feat_post(
    const float* __restrict__ y, const float* __restrict__ lin_b,
    const float* __restrict__ ln_g, const float* __restrict__ ln_b,
    const float* __restrict__ emb, float* __restrict__ xout)
{
    int n = (blockIdx.x << 2) + (threadIdx.x >> 6);
    int c = threadIdx.x & 63;
    size_t base = (size_t)n * 64 + c;
    float v = y[base] + lin_b[c];
    float mean = wave_sum64(v) * 0.015625f;
    float t = v - mean;
    float var = wave_sum64(t * t) * 0.015625f;
    float vn = t * (1.0f / sqrtf(var + 1e-5f)) * ln_g[c] + ln_b[c];
    float g = gelu_exact(vn);
    float e = emb[base];
    float nrm = sqrtf(wave_sum64(e * e));
    xout[base] = g + e / fmaxf(nrm, 1e-12f);
}

// ---------------------------------------------------------------------------
// Edge aggregation: one wave per destination node, nt types per dispatch.
// z[n][tt*256 + h*64 + d] = (sum_e p_e,h * x[src_e,d]) / S[n,h].
// row_ptr values are PER-TYPE-relative; col must be indexed with the t*EPN
// segment base (round-3 bug: col[e] read type-0's columns for all types).
// ---------------------------------------------------------------------------
__global__ __launch_bounds__(256) void k_edge2(
    const float* __restrict__ x, const float* __restrict__ s_all,
    const int* __restrict__ row_ptr, const int* __restrict__ col,
    float* __restrict__ z, int t0, int nt)
{
    int n = (blockIdx.x << 2) + (threadIdx.x >> 6);   // grid = NN/4 exactly
    int lane = threadIdx.x & 63;
    int zrow = nt * 256;
    for (int tt = 0; tt < nt; ++tt) {
        int t = t0 + tt;
        int rp0 = row_ptr[t * (NN + 1) + n];
        int rp1 = row_ptr[t * (NN + 1) + n + 1];
        const int* colt = col + (size_t)t * EPN;      // per-type segment base
        const float4 sd = *(const float4*)&s_all[(size_t)n * 64 + t * 8 + 4];
        float z0 = 0.f, z1 = 0.f, z2 = 0.f, z3 = 0.f;
        float S0 = 0.f, S1 = 0.f, S2 = 0.f, S3 = 0.f;
        #pragma unroll 2
        for (int e = rp0; e < rp1; ++e) {
            int s = colt[e];                                  // wave-uniform
            const float4 ss = *(const float4*)&s_all[(size_t)s * 64 + t * 8];
            float l0 = ss.x + sd.x, l1 = ss.y + sd.y;
            float l2 = ss.z + sd.z, l3 = ss.w + sd.w;
            l0 = l0 > 0.f ? l0 : 0.2f * l0;
            l1 = l1 > 0.f ? l1 : 0.2f * l1;
            l2 = l2 > 0.f ? l2 : 0.2f * l2;
            l3 = l3 > 0.f ? l3 : 0.2f * l3;
            float p0 = __expf(l0), p1 = __expf(l1);
            float p2 = __expf(l2), p3 = __expf(l3);
            S0 += p0; S1 += p1; S2 += p2; S3 += p3;
            float xv = x[(size_t)s * 64 + lane];              // coalesced 256B
            z0 = fmaf(p0, xv, z0);
            z1 = fmaf(p1, xv, z1);
            z2 = fmaf(p2, xv, z2);
            z3 = fmaf(p3, xv, z3);
        }
        size_t zb = (size_t)n * zrow + tt * 256 + lane;
        z[zb]       = z0 / S0;
        z[zb + 64]  = z1 / S1;
        z[zb + 128] = z2 / S2;
        z[zb + 192] = z3 / S3;
    }
}

// ---------------------------------------------------------------------------
extern "C" void kernel_launch(void* const* d_in, const int* in_sizes, int n_in,
                              void* d_out, int out_size, void* d_ws, size_t ws_size,
                              hipStream_t stream) {
    const float* fm    = (const float*)d_in[0];
    const float* emb   = (const float*)d_in[1];
    const float* lin_w = (const float*)d_in[2];
    const float* lin_b = (const float*)d_in[3];
    const float* ln_g  = (const float*)d_in[4];
    const float* ln_b  = (const float*)d_in[5];
    const float* Wsrc  = (const float*)d_in[6];
    const float* Wdst  = (const float*)d_in[7];
    const float* asrc  = (const float*)d_in[8];
    const float* adst  = (const float*)d_in[9];
    const float* cbias = (const float*)d_in[10];
    const int*   ei    = (const int*)d_in[11];
    float* out = (float*)d_out;
    (void)in_sizes; (void)n_in; (void)out_size;

    char* w = (char*)d_ws;
    size_t off = 0;
    auto alloc = [&](size_t bytes) -> void* {
        void* p = w + off;
        off += (bytes + 255) & ~(size_t)255;
        return p;
    };
    float* wcoll   = (float*)alloc((size_t)LL * 64 * 64 * 4);
    float* bsum    = (float*)alloc((size_t)LL * 64 * 4);
    float* bproj   = (float*)alloc((size_t)LL * TT * 256 * 64 * 4);
    int*   row_ptr = (int*)  alloc((size_t)TT * (NN + 1) * 4);
    int*   cursor  = (int*)  alloc((size_t)TT * NN * 4);
    int*   colarr  = (int*)  alloc((size_t)TT * EPN * 4);
    int*   csum    = (int*)  alloc((size_t)TT * NCH * 4);
    int*   cbase   = (int*)  alloc((size_t)TT * NCH * 4);
    float* x       = (float*)alloc((size_t)NN * 64 * 4);
    float* s_all   = (float*)alloc((size_t)NN * 64 * 4);
    float* acc     = (float*)alloc((size_t)NN * 64 * 4);
    // NT = types fused per projection GEMM, limited by remaining workspace.
    size_t rem = (ws_size > off) ? (ws_size - off) : 0;
    int NT = 1;
    if (rem >= (size_t)NN * 256 * 4 * 4 + (16u << 20)) NT = 4;
    else if (rem >= (size_t)NN * 256 * 4 * 2 + (16u << 20)) NT = 2;
    float* z = (float*)alloc((size_t)NN * 256 * NT * 4);

    hipMemsetAsync(cursor, 0, (size_t)TT * NN * 4, stream);
    k_prep<<<512, 256, 0, stream>>>(Wsrc, Wdst, asrc, adst, cbias, wcoll, bproj, bsum);
    k_hist<<<(TT * EE + 255) / 256, 256, 0, stream>>>(ei, cursor);
    k_scan1<<<TT * NCH, 256, 0, stream>>>(cursor, csum);
    k_scan2<<<1, 64, 0, stream>>>(csum, cbase, row_ptr);
    k_scan3<<<TT * NCH, 256, 0, stream>>>(cursor, cbase, row_ptr);
    k_scatter<<<(TT * EPN + 255) / 256, 256, 0, stream>>>(ei, cursor, colarr);

    const int GB = (NN + 127) / 128;   // 782
    // feature transform
    k_gemm_rt<0><<<GB, 128, 0, stream>>>(fm, lin_w, nullptr, acc, nullptr, 256, NN);
    k_feat_post<<<NN / 4, 256, 0, stream>>>(acc, lin_b, ln_g, ln_b, emb, x);

    const int nb = TT / NT;
    for (int l = 0; l < LL; ++l) {
        // collapsed attention-logit projection: s_all = x @ wcoll_l  [N,64]
        k_gemm_rt<0><<<GB, 128, 0, stream>>>(x, wcoll + l * 4096, nullptr,
                                             s_all, nullptr, 64, NN);
        float* dest = (l == 0) ? x : out;
        for (int b = 0; b < nb; ++b) {
            k_edge2<<<NN / 4, 256, 0, stream>>>(
                x, s_all, row_ptr, colarr, z, b * NT, NT);
            const float* bp = bproj + ((size_t)l * 1024 + (size_t)b * NT * 256) * 64;
            int K = NT * 256;
            if (nb == 1) {
                k_gemm_rt<2><<<GB, 128, 0, stream>>>(z, bp, nullptr, dest,
                                                     bsum + l * 64, K, NN);
            } else if (b == 0) {
                k_gemm_rt<0><<<GB, 128, 0, stream>>>(z, bp, nullptr, acc,
                                                     nullptr, K, NN);
            } else if (b < nb - 1) {
                k_gemm_rt<1><<<GB, 128, 0, stream>>>(z, bp, acc, acc,
                                                     nullptr, K, NN);
            } else {
                k_gemm_rt<3><<<GB, 128, 0, stream>>>(z, bp, acc, dest,
                                                     bsum + l * 64, K, NN);
            }
        }
    }
}

// Round 5
// 1376.330 us; speedup vs baseline: 1.0545x; 1.0545x over previous
//
#include <hip/hip_runtime.h>
#include <hip/hip_bf16.h>
#include <cstdint>

#define NN   100000
#define TT   4
#define EE   250000
#define LL   2
#define NCH  49            // ceil(NN/2048)
#define EPN  (EE + NN)     // 350000
#define N64  ((size_t)NN * 64)

static __device__ __forceinline__ float gelu_exact(float v) {
    return 0.5f * v * (1.0f + erff(v * 0.7071067811865476f));
}
static __device__ __forceinline__ float wave_sum64(float v) {
    #pragma unroll
    for (int m = 32; m; m >>= 1) v += __shfl_xor(v, m, 64);
    return v;
}

// ---------------------------------------------------------------------------
// Prep: collapsed logit weights w_coll[l][d][col] (col = t*8 + side*4 + h),
// projection Bproj[(l*1024 + t*256 + h*64 + d)*64 + c] = 0.25*W_src[l,t,d,h*64+c],
// bias_sum[l][c] = sum_t conv_bias[l,t,c].
// ---------------------------------------------------------------------------
__global__ __launch_bounds__(256) void k_prep(
    const float* __restrict__ Wsrc, const float* __restrict__ Wdst,
    const float* __restrict__ asrc, const float* __restrict__ adst,
    const float* __restrict__ cb,
    float* __restrict__ wcoll, float* __restrict__ bproj, float* __restrict__ bsum)
{
    int id = blockIdx.x * 256 + threadIdx.x;   // grid = 131072 exactly
    {   // Bproj: id = ((l*1024 + t*256 + h*64 + d)*64 + c)
        int c = id & 63;
        int d = (id >> 6) & 63;
        int h = (id >> 12) & 3;
        int t = (id >> 14) & 3;
        int l = (id >> 16) & 1;
        bproj[id] = 0.25f * Wsrc[(((l * 4 + t) * 64 + d) * 256) + h * 64 + c];
    }
    if (id < LL * 64 * 64) {   // w_coll
        int col = id & 63;
        int d   = (id >> 6) & 63;
        int l   = id >> 12;
        int t = col >> 3, side = (col >> 2) & 1, h = col & 3;
        const float* W = side ? Wdst : Wsrc;
        const float* a = side ? adst : asrc;
        int wb = ((l * 4 + t) * 64 + d) * 256 + h * 64;
        int ab = ((l * 4 + t) * 4 + h) * 64;
        float s = 0.f;
        #pragma unroll 8
        for (int c2 = 0; c2 < 64; ++c2) s = fmaf(W[wb + c2], a[ab + c2], s);
        wcoll[id] = s;
    }
    if (id < LL * 64) {        // bias_sum
        int l = id >> 6, c = id & 63;
        float s = 0.f;
        for (int t = 0; t < TT; ++t) s += cb[(l * 4 + t) * 64 + c];
        bsum[id] = s;
    }
}

// ---------------------------------------------------------------------------
// CSR build (unchanged, verified)
// ---------------------------------------------------------------------------
__global__ void k_hist(const int* __restrict__ ei, int* __restrict__ cursor) {
    int id = blockIdx.x * 256 + threadIdx.x;
    if (id >= TT * EE) return;
    int t = id / EE, e = id - t * EE;
    int d = ei[(t * 2 + 1) * EE + e];
    atomicAdd(&cursor[t * NN + d], 1);
}

__global__ __launch_bounds__(256) void k_scan1(const int* __restrict__ deg,
                                               int* __restrict__ csum) {
    int b = blockIdx.x, t = b / NCH, cc = b - t * NCH;
    int tid = threadIdx.x;
    int base = cc * 2048 + tid * 8;
    int s = 0;
    #pragma unroll
    for (int i = 0; i < 8; ++i) {
        int idx = base + i;
        if (idx < NN) s += deg[t * NN + idx] + 1;   // +1: self loop
    }
    #pragma unroll
    for (int m = 32; m; m >>= 1) s += __shfl_xor(s, m, 64);
    __shared__ int ws4[4];
    int lane = tid & 63, wid = tid >> 6;
    if (lane == 0) ws4[wid] = s;
    __syncthreads();
    if (tid == 0) csum[b] = ws4[0] + ws4[1] + ws4[2] + ws4[3];
}

__global__ void k_scan2(const int* __restrict__ csum, int* __restrict__ cbase,
                        int* __restrict__ row_ptr) {
    int t = threadIdx.x;
    if (t >= TT) return;
    int base = 0;
    for (int c = 0; c < NCH; ++c) {
        cbase[t * NCH + c] = base;
        base += csum[t * NCH + c];
    }
    row_ptr[t * (NN + 1) + NN] = base;   // = EE + NN
}

__global__ __launch_bounds__(256) void k_scan3(int* __restrict__ cursor,
                                               const int* __restrict__ cbase,
                                               int* __restrict__ row_ptr) {
    int b = blockIdx.x, t = b / NCH, cc = b - t * NCH;
    int tid = threadIdx.x, lane = tid & 63, wid = tid >> 6;
    int base = cc * 2048 + tid * 8;
    int vals[8], ts = 0;
    #pragma unroll
    for (int i = 0; i < 8; ++i) {
        int idx = base + i;
        int v = (idx < NN) ? cursor[t * NN + idx] + 1 : 0;
        vals[i] = v; ts += v;
    }
    int v = ts;
    #pragma unroll
    for (int off = 1; off < 64; off <<= 1) {
        int u = __shfl_up(v, off, 64);
        if (lane >= off) v += u;
    }
    __shared__ int wt[4];
    if (lane == 63) wt[wid] = v;
    __syncthreads();
    int wbase = 0;
    for (int w = 0; w < wid; ++w) wbase += wt[w];
    int run = cbase[t * NCH + cc] + wbase + (v - ts);
    #pragma unroll
    for (int i = 0; i < 8; ++i) {
        int idx = base + i;
        if (idx < NN) {
            row_ptr[t * (NN + 1) + idx] = run;
            cursor[t * NN + idx] = run;     // becomes scatter write-head
        }
        run += vals[i];
    }
}

__global__ void k_scatter(const int* __restrict__ ei, int* __restrict__ cursor,
                          int* __restrict__ col) {
    int id = blockIdx.x * 256 + threadIdx.x;
    if (id >= TT * EPN) return;
    int t = id / EPN, r = id - t * EPN;
    int s, d;
    if (r < EE) { s = ei[t * 2 * EE + r]; d = ei[(t * 2 + 1) * EE + r]; }
    else        { s = d = r - EE; }
    int pos = atomicAdd(&cursor[t * NN + d], 1);
    col[(size_t)t * EPN + pos] = s;
}

// ---------------------------------------------------------------------------
// Split-K tiled GEMM: P[y] = A[:, y*K/S:(y+1)*K/S] @ B[y-slice]   (S partials)
// 256 threads (4 waves/block), RT=128 rows, 4x8 register tile/thread:
//   3 ds_read_b128 per 32 FMA.  LDS 25 KB -> 6 blocks/CU; grid 782*S blocks
//   -> S=2: 6.1 blk/CU, S=4: 12.2 -> ~24 waves/CU (round-4 bug: 128-thread
//   blocks + grid 3/CU = 13% occupancy, latency-bound at VALU 28%).
// Partials carry no epilogue; k_combine / k_feat_post fold them.
// ---------------------------------------------------------------------------
template <int S>
__global__ __launch_bounds__(256, 4) void k_gemm(
    const float* __restrict__ A, const float* __restrict__ B,
    float* __restrict__ P, int K, int nrows)
{
    constexpr int KC = 32, RT = 128, LDA = RT + 4;  // LDA=132 floats (33 f4)
    __shared__ float sA[KC * LDA];   // 16.9 KB
    __shared__ float sB[KC * 64];    // 8 KB
    const int tid = threadIdx.x;               // 0..255
    const int y = blockIdx.y;                  // K-slice
    const int Ks = K / S;
    const int k0 = y * Ks;
    const int rowbase = blockIdx.x * RT;
    const int jc = tid & 7;                    // cols jc*8 .. jc*8+7
    const int rg = tid >> 3;                   // rows rg*4 .. rg*4+3 (0..31)
    const float4* sA4 = (const float4*)sA;
    const float4* sB4 = (const float4*)sB;

    float acc[4][8];
    #pragma unroll
    for (int i = 0; i < 4; ++i)
        #pragma unroll
        for (int j = 0; j < 8; ++j) acc[i][j] = 0.f;

    for (int kc = 0; kc < Ks; kc += KC) {
        __syncthreads();
        // stage B chunk: 32x64 floats = 512 float4, linear, conflict-free
        {
            const float4* Bg = (const float4*)(B + (size_t)(k0 + kc) * 64);
            float4* sBw = (float4*)sB;
            sBw[tid] = Bg[tid];
            sBw[tid + 256] = Bg[tid + 256];
        }
        // stage A chunk: 128 rows x 32 cols = 1024 f4, coalesced, transposed
        #pragma unroll
        for (int i = 0; i < 4; ++i) {
            int f = tid + i * 256;     // 0..1023
            int r = f >> 3;            // 0..127
            int cg = f & 7;            // float4 within 32-col chunk
            int row = rowbase + r;
            float4 v = (row < nrows)
                ? *(const float4*)(A + (size_t)row * K + k0 + kc + cg * 4)
                : make_float4(0.f, 0.f, 0.f, 0.f);
            int b0 = (cg * 4) * LDA + r;
            sA[b0]           = v.x;
            sA[b0 + LDA]     = v.y;
            sA[b0 + 2 * LDA] = v.z;
            sA[b0 + 3 * LDA] = v.w;
        }
        __syncthreads();
        #pragma unroll 4
        for (int k = 0; k < KC; ++k) {
            float4 a0 = sA4[k * 33 + rg];          // rows rg*4..+3, bank-clean
            float4 b0 = sB4[k * 16 + jc * 2];      // 2-way broadcast (free)
            float4 b1 = sB4[k * 16 + jc * 2 + 1];
            float av[4] = {a0.x, a0.y, a0.z, a0.w};
            float bv[8] = {b0.x, b0.y, b0.z, b0.w, b1.x, b1.y, b1.z, b1.w};
            #pragma unroll
            for (int i = 0; i < 4; ++i)
                #pragma unroll
                for (int j = 0; j < 8; ++j)
                    acc[i][j] = fmaf(av[i], bv[j], acc[i][j]);
        }
    }
    float* Pp = P + (size_t)y * N64;
    #pragma unroll
    for (int i = 0; i < 4; ++i) {
        int row = rowbase + rg * 4 + i;
        if (row < nrows) {
            size_t coff = (size_t)row * 64 + jc * 8;
            float4 r0, r1;
            r0.x = acc[i][0]; r0.y = acc[i][1]; r0.z = acc[i][2]; r0.w = acc[i][3];
            r1.x = acc[i][4]; r1.y = acc[i][5]; r1.z = acc[i][6]; r1.w = acc[i][7];
            *(float4*)(Pp + coff) = r0;
            *(float4*)(Pp + coff + 4) = r1;
        }
    }
}

// ---------------------------------------------------------------------------
// Partial combiner.  MODE 0: accbuf = sum(P)      MODE 1: accbuf += sum(P)
// MODE 2: out = gelu((accbuf + sum(P) + bias)*0.25)
// MODE 3: out = gelu((sum(P) + bias)*0.25)
// ---------------------------------------------------------------------------
template <int S, int MODE>
__global__ void k_combine(const float* __restrict__ P, float* __restrict__ accbuf,
                          const float* __restrict__ bias, float* __restrict__ out)
{
    int i4 = blockIdx.x * 256 + threadIdx.x;   // float4 index
    if (i4 >= NN * 16) return;
    float4 s = ((const float4*)P)[i4];
    #pragma unroll
    for (int y = 1; y < S; ++y) {
        float4 p = ((const float4*)(P + (size_t)y * N64))[i4];
        s.x += p.x; s.y += p.y; s.z += p.z; s.w += p.w;
    }
    if (MODE == 0) { ((float4*)accbuf)[i4] = s; return; }
    if (MODE == 1) {
        float4 a = ((const float4*)accbuf)[i4];
        s.x += a.x; s.y += a.y; s.z += a.z; s.w += a.w;
        ((float4*)accbuf)[i4] = s; return;
    }
    if (MODE == 2) {
        float4 a = ((const float4*)accbuf)[i4];
        s.x += a.x; s.y += a.y; s.z += a.z; s.w += a.w;
    }
    int c = (i4 * 4) & 63;
    float4 b = *(const float4*)&bias[c];
    float4 r;
    r.x = gelu_exact((s.x + b.x) * 0.25f);
    r.y = gelu_exact((s.y + b.y) * 0.25f);
    r.z = gelu_exact((s.z + b.z) * 0.25f);
    r.w = gelu_exact((s.w + b.w) * 0.25f);
    ((float4*)out)[i4] = r;
}

// ---------------------------------------------------------------------------
// Feature epilogue: x = gelu(LN(P0 + P1 + lin_b)) + l2norm(emb).  Wave/row.
// ---------------------------------------------------------------------------
__global__ __launch_bounds__(256) void k_feat_post(
    const float* __restrict__ P, const float* __restrict__ lin_b,
    const float* __restrict__ ln_g, const float* __restrict__ ln_b,
    const float* __restrict__ emb, float* __restrict__ xout)
{
    int n = (blockIdx.x << 2) + (threadIdx.x >> 6);
    int c = threadIdx.x & 63;
    size_t base = (size_t)n * 64 + c;
    float v = P[base] + P[base + N64] + lin_b[c];
    float mean = wave_sum64(v) * 0.015625f;
    float t = v - mean;
    float var = wave_sum64(t * t) * 0.015625f;
    float vn = t * (1.0f / sqrtf(var + 1e-5f)) * ln_g[c] + ln_b[c];
    float g = gelu_exact(vn);
    float e = emb[base];
    float nrm = sqrtf(wave_sum64(e * e));
    xout[base] = g + e / fmaxf(nrm, 1e-12f);
}

// ---------------------------------------------------------------------------
// Edge aggregation: one wave per destination node, nt types per dispatch.
// z[n][tt*256 + h*64 + d] = (sum_e p_e,h * x[src_e,d]) / S[n,h].
// row_ptr values are per-type-relative; col indexed via t*EPN segment base.
// ---------------------------------------------------------------------------
__global__ __launch_bounds__(256) void k_edge2(
    const float* __restrict__ x, const float* __restrict__ s_all,
    const int* __restrict__ row_ptr, const int* __restrict__ col,
    float* __restrict__ z, int t0, int nt)
{
    int n = (blockIdx.x << 2) + (threadIdx.x >> 6);   // grid = NN/4 exactly
    int lane = threadIdx.x & 63;
    int zrow = nt * 256;
    for (int tt = 0; tt < nt; ++tt) {
        int t = t0 + tt;
        int rp0 = row_ptr[t * (NN + 1) + n];
        int rp1 = row_ptr[t * (NN + 1) + n + 1];
        const int* colt = col + (size_t)t * EPN;      // per-type segment base
        const float4 sd = *(const float4*)&s_all[(size_t)n * 64 + t * 8 + 4];
        float z0 = 0.f, z1 = 0.f, z2 = 0.f, z3 = 0.f;
        float S0 = 0.f, S1 = 0.f, S2 = 0.f, S3 = 0.f;
        #pragma unroll 2
        for (int e = rp0; e < rp1; ++e) {
            int s = colt[e];                                  // wave-uniform
            const float4 ss = *(const float4*)&s_all[(size_t)s * 64 + t * 8];
            float l0 = ss.x + sd.x, l1 = ss.y + sd.y;
            float l2 = ss.z + sd.z, l3 = ss.w + sd.w;
            l0 = l0 > 0.f ? l0 : 0.2f * l0;
            l1 = l1 > 0.f ? l1 : 0.2f * l1;
            l2 = l2 > 0.f ? l2 : 0.2f * l2;
            l3 = l3 > 0.f ? l3 : 0.2f * l3;
            float p0 = __expf(l0), p1 = __expf(l1);
            float p2 = __expf(l2), p3 = __expf(l3);
            S0 += p0; S1 += p1; S2 += p2; S3 += p3;
            float xv = x[(size_t)s * 64 + lane];              // coalesced 256B
            z0 = fmaf(p0, xv, z0);
            z1 = fmaf(p1, xv, z1);
            z2 = fmaf(p2, xv, z2);
            z3 = fmaf(p3, xv, z3);
        }
        size_t zb = (size_t)n * zrow + tt * 256 + lane;
        z[zb]       = z0 / S0;
        z[zb + 64]  = z1 / S1;
        z[zb + 128] = z2 / S2;
        z[zb + 192] = z3 / S3;
    }
}

// ---------------------------------------------------------------------------
extern "C" void kernel_launch(void* const* d_in, const int* in_sizes, int n_in,
                              void* d_out, int out_size, void* d_ws, size_t ws_size,
                              hipStream_t stream) {
    const float* fm    = (const float*)d_in[0];
    const float* emb   = (const float*)d_in[1];
    const float* lin_w = (const float*)d_in[2];
    const float* lin_b = (const float*)d_in[3];
    const float* ln_g  = (const float*)d_in[4];
    const float* ln_b  = (const float*)d_in[5];
    const float* Wsrc  = (const float*)d_in[6];
    const float* Wdst  = (const float*)d_in[7];
    const float* asrc  = (const float*)d_in[8];
    const float* adst  = (const float*)d_in[9];
    const float* cbias = (const float*)d_in[10];
    const int*   ei    = (const int*)d_in[11];
    float* out = (float*)d_out;
    (void)in_sizes; (void)n_in; (void)out_size;

    char* w = (char*)d_ws;
    size_t off = 0;
    auto alloc = [&](size_t bytes) -> void* {
        void* p = w + off;
        off += (bytes + 255) & ~(size_t)255;
        return p;
    };
    float* wcoll   = (float*)alloc((size_t)LL * 64 * 64 * 4);
    float* bsum    = (float*)alloc((size_t)LL * 64 * 4);
    float* bproj   = (float*)alloc((size_t)LL * TT * 256 * 64 * 4);
    int*   row_ptr = (int*)  alloc((size_t)TT * (NN + 1) * 4);
    int*   cursor  = (int*)  alloc((size_t)TT * NN * 4);
    int*   colarr  = (int*)  alloc((size_t)TT * EPN * 4);
    int*   csum    = (int*)  alloc((size_t)TT * NCH * 4);
    int*   cbase   = (int*)  alloc((size_t)TT * NCH * 4);
    float* x       = (float*)alloc(N64 * 4);
    float* s_all   = (float*)alloc(N64 * 4);
    float* acc     = (float*)alloc(N64 * 4);
    float* P       = (float*)alloc(N64 * 4 * 4);   // up to 4 split-K partials
    // NT = types fused per projection GEMM, limited by remaining workspace.
    size_t rem = (ws_size > off) ? (ws_size - off) : 0;
    int NT = (rem >= (size_t)NN * 256 * 4 * 4 + (16u << 20)) ? 4 : 1;
    float* z = (float*)alloc((size_t)NN * 256 * NT * 4);

    hipMemsetAsync(cursor, 0, (size_t)TT * NN * 4, stream);
    k_prep<<<512, 256, 0, stream>>>(Wsrc, Wdst, asrc, adst, cbias, wcoll, bproj, bsum);
    k_hist<<<(TT * EE + 255) / 256, 256, 0, stream>>>(ei, cursor);
    k_scan1<<<TT * NCH, 256, 0, stream>>>(cursor, csum);
    k_scan2<<<1, 64, 0, stream>>>(csum, cbase, row_ptr);
    k_scan3<<<TT * NCH, 256, 0, stream>>>(cursor, cbase, row_ptr);
    k_scatter<<<(TT * EPN + 255) / 256, 256, 0, stream>>>(ei, cursor, colarr);

    const int GB = (NN + 127) / 128;   // 782
    const int CB = (NN * 16 + 255) / 256;
    // feature transform: fm @ lin_w (K=256, 2 partials) -> LN/gelu/emb epilogue
    k_gemm<2><<<dim3(GB, 2), 256, 0, stream>>>(fm, lin_w, P, 256, NN);
    k_feat_post<<<NN / 4, 256, 0, stream>>>(P, lin_b, ln_g, ln_b, emb, x);

    for (int l = 0; l < LL; ++l) {
        // collapsed attention-logit projection: s_all = x @ wcoll_l  [N,64]
        k_gemm<1><<<dim3(GB, 1), 256, 0, stream>>>(x, wcoll + l * 4096, s_all, 64, NN);
        float* dest = (l == 0) ? x : out;
        if (NT == 4) {
            k_edge2<<<NN / 4, 256, 0, stream>>>(x, s_all, row_ptr, colarr, z, 0, 4);
            k_gemm<4><<<dim3(GB, 4), 256, 0, stream>>>(
                z, bproj + (size_t)l * 1024 * 64, P, 1024, NN);
            k_combine<4, 3><<<CB, 256, 0, stream>>>(P, nullptr, bsum + l * 64, dest);
        } else {
            for (int t = 0; t < TT; ++t) {
                k_edge2<<<NN / 4, 256, 0, stream>>>(x, s_all, row_ptr, colarr, z, t, 1);
                k_gemm<2><<<dim3(GB, 2), 256, 0, stream>>>(
                    z, bproj + ((size_t)l * 1024 + t * 256) * 64, P, 256, NN);
                if (t == 0)
                    k_combine<2, 0><<<CB, 256, 0, stream>>>(P, acc, nullptr, nullptr);
                else if (t < TT - 1)
                    k_combine<2, 1><<<CB, 256, 0, stream>>>(P, acc, nullptr, nullptr);
                else
                    k_combine<2, 2><<<CB, 256, 0, stream>>>(P, acc, bsum + l * 64, dest);
            }
        }
    }
}

// Round 6
// 1054.900 us; speedup vs baseline: 1.3758x; 1.3047x over previous
//
#include <hip/hip_runtime.h>
#include <hip/hip_bf16.h>
#include <cstdint>

#define NN   100000
#define TT   4
#define EE   250000
#define LL   2
#define NCH  49            // ceil(NN/2048)
#define EPN  (EE + NN)     // 350000
#define N64  ((size_t)NN * 64)

typedef unsigned short ushort_t;
typedef __attribute__((ext_vector_type(8))) short bf16x8;
typedef __attribute__((ext_vector_type(16))) float floatx16;

static __device__ __forceinline__ float gelu_exact(float v) {
    return 0.5f * v * (1.0f + erff(v * 0.7071067811865476f));
}
static __device__ __forceinline__ float wave_sum64(float v) {
    #pragma unroll
    for (int m = 32; m; m >>= 1) v += __shfl_xor(v, m, 64);
    return v;
}
// fp32 -> bf16 round-to-nearest-even (finite inputs only)
static __device__ __forceinline__ ushort_t f2bf(float f) {
    unsigned u = __float_as_uint(f);
    u += 0x7FFFu + ((u >> 16) & 1u);
    return (ushort_t)(u >> 16);
}
static __device__ __forceinline__ float bf2f(ushort_t h) {
    return __uint_as_float((unsigned)h << 16);
}

// ---------------------------------------------------------------------------
// Prep: all GEMM B-operands as TRANSPOSED split-bf16 planes [n][k]:
//  wcollT[l][col][d]  (K=64)   col = t*8+side*4+h, from W·a dot products
//  linwT[c][k]        (K=256)  from lin_w[k][c]
//  bprojT[l][c][kidx] (K=1024) kidx = t*256+h*64+d, val 0.25*W_src[l,t,d,h*64+c]
//  bsum[l][c] = sum_t conv_bias
// ---------------------------------------------------------------------------
__global__ __launch_bounds__(256) void k_prep(
    const float* __restrict__ Wsrc, const float* __restrict__ Wdst,
    const float* __restrict__ asrc, const float* __restrict__ adst,
    const float* __restrict__ cb, const float* __restrict__ lin_w,
    ushort_t* __restrict__ wcTh, ushort_t* __restrict__ wcTl,
    ushort_t* __restrict__ lwTh, ushort_t* __restrict__ lwTl,
    ushort_t* __restrict__ bpTh, ushort_t* __restrict__ bpTl,
    float* __restrict__ bsum)
{
    int id = blockIdx.x * 256 + threadIdx.x;   // grid = 131072 exactly
    {   // bprojT: id = ((((l*4+t)*4+h)*64 + c)*64 + d)
        int d = id & 63;
        int c = (id >> 6) & 63;
        int h = (id >> 12) & 3;
        int t = (id >> 14) & 3;
        int l = (id >> 16) & 1;
        float v = 0.25f * Wsrc[(((l * 4 + t) * 64 + d) * 256) + h * 64 + c];
        int dst = (l * 64 + c) * 1024 + (t * 256 + h * 64 + d);
        ushort_t hh = f2bf(v);
        bpTh[dst] = hh;
        bpTl[dst] = f2bf(v - bf2f(hh));
    }
    if (id < LL * 64 * 64) {   // wcollT
        int d   = id & 63;
        int col = (id >> 6) & 63;
        int l   = (id >> 12) & 1;
        int t = col >> 3, side = (col >> 2) & 1, h = col & 3;
        const float* W = side ? Wdst : Wsrc;
        const float* a = side ? adst : asrc;
        int wb = ((l * 4 + t) * 64 + d) * 256 + h * 64;
        int ab = ((l * 4 + t) * 4 + h) * 64;
        float s = 0.f;
        #pragma unroll 8
        for (int c2 = 0; c2 < 64; ++c2) s = fmaf(W[wb + c2], a[ab + c2], s);
        int dst = (l * 64 + col) * 64 + d;
        ushort_t hh = f2bf(s);
        wcTh[dst] = hh;
        wcTl[dst] = f2bf(s - bf2f(hh));
    }
    if (id < 64 * 256) {       // linwT: c = id>>8, k = id&255
        int k = id & 255, c = id >> 8;
        float v = lin_w[k * 64 + c];
        ushort_t hh = f2bf(v);
        lwTh[c * 256 + k] = hh;
        lwTl[c * 256 + k] = f2bf(v - bf2f(hh));
    }
    if (id < LL * 64) {        // bias_sum
        int l = id >> 6, c = id & 63;
        float s = 0.f;
        for (int t = 0; t < TT; ++t) s += cb[(l * 4 + t) * 64 + c];
        bsum[id] = s;
    }
}

// ---------------------------------------------------------------------------
// CSR build (unchanged, verified)
// ---------------------------------------------------------------------------
__global__ void k_hist(const int* __restrict__ ei, int* __restrict__ cursor) {
    int id = blockIdx.x * 256 + threadIdx.x;
    if (id >= TT * EE) return;
    int t = id / EE, e = id - t * EE;
    int d = ei[(t * 2 + 1) * EE + e];
    atomicAdd(&cursor[t * NN + d], 1);
}

__global__ __launch_bounds__(256) void k_scan1(const int* __restrict__ deg,
                                               int* __restrict__ csum) {
    int b = blockIdx.x, t = b / NCH, cc = b - t * NCH;
    int tid = threadIdx.x;
    int base = cc * 2048 + tid * 8;
    int s = 0;
    #pragma unroll
    for (int i = 0; i < 8; ++i) {
        int idx = base + i;
        if (idx < NN) s += deg[t * NN + idx] + 1;   // +1: self loop
    }
    #pragma unroll
    for (int m = 32; m; m >>= 1) s += __shfl_xor(s, m, 64);
    __shared__ int ws4[4];
    int lane = tid & 63, wid = tid >> 6;
    if (lane == 0) ws4[wid] = s;
    __syncthreads();
    if (tid == 0) csum[b] = ws4[0] + ws4[1] + ws4[2] + ws4[3];
}

__global__ void k_scan2(const int* __restrict__ csum, int* __restrict__ cbase,
                        int* __restrict__ row_ptr) {
    int t = threadIdx.x;
    if (t >= TT) return;
    int base = 0;
    for (int c = 0; c < NCH; ++c) {
        cbase[t * NCH + c] = base;
        base += csum[t * NCH + c];
    }
    row_ptr[t * (NN + 1) + NN] = base;   // = EE + NN
}

__global__ __launch_bounds__(256) void k_scan3(int* __restrict__ cursor,
                                               const int* __restrict__ cbase,
                                               int* __restrict__ row_ptr) {
    int b = blockIdx.x, t = b / NCH, cc = b - t * NCH;
    int tid = threadIdx.x, lane = tid & 63, wid = tid >> 6;
    int base = cc * 2048 + tid * 8;
    int vals[8], ts = 0;
    #pragma unroll
    for (int i = 0; i < 8; ++i) {
        int idx = base + i;
        int v = (idx < NN) ? cursor[t * NN + idx] + 1 : 0;
        vals[i] = v; ts += v;
    }
    int v = ts;
    #pragma unroll
    for (int off = 1; off < 64; off <<= 1) {
        int u = __shfl_up(v, off, 64);
        if (lane >= off) v += u;
    }
    __shared__ int wt[4];
    if (lane == 63) wt[wid] = v;
    __syncthreads();
    int wbase = 0;
    for (int w = 0; w < wid; ++w) wbase += wt[w];
    int run = cbase[t * NCH + cc] + wbase + (v - ts);
    #pragma unroll
    for (int i = 0; i < 8; ++i) {
        int idx = base + i;
        if (idx < NN) {
            row_ptr[t * (NN + 1) + idx] = run;
            cursor[t * NN + idx] = run;     // becomes scatter write-head
        }
        run += vals[i];
    }
}

__global__ void k_scatter(const int* __restrict__ ei, int* __restrict__ cursor,
                          int* __restrict__ col) {
    int id = blockIdx.x * 256 + threadIdx.x;
    if (id >= TT * EPN) return;
    int t = id / EPN, r = id - t * EPN;
    int s, d;
    if (r < EE) { s = ei[t * 2 * EE + r]; d = ei[(t * 2 + 1) * EE + r]; }
    else        { s = d = r - EE; }
    int pos = atomicAdd(&cursor[t * NN + d], 1);
    col[(size_t)t * EPN + pos] = s;
}

// ---------------------------------------------------------------------------
// fp32 -> split-bf16 plane converter (for fm input)
// ---------------------------------------------------------------------------
__global__ void k_split(const float* __restrict__ in, ushort_t* __restrict__ hi,
                        ushort_t* __restrict__ lo, int n4) {
    int i = blockIdx.x * 256 + threadIdx.x;
    if (i >= n4) return;
    float4 v = ((const float4*)in)[i];
    ushort_t h0 = f2bf(v.x), h1 = f2bf(v.y), h2 = f2bf(v.z), h3 = f2bf(v.w);
    ushort4 hv = make_ushort4(h0, h1, h2, h3);
    ushort4 lv = make_ushort4(f2bf(v.x - bf2f(h0)), f2bf(v.y - bf2f(h1)),
                              f2bf(v.z - bf2f(h2)), f2bf(v.w - bf2f(h3)));
    ((ushort4*)hi)[i] = hv;
    ((ushort4*)lo)[i] = lv;
}

// ---------------------------------------------------------------------------
// Split-bf16 MFMA GEMM: C[N,64] = A[N,K] @ B[K,64] via 3 products
// (ah·bh + al·bh + ah·bl), mfma_f32_32x32x16_bf16.
// A: hi/lo planes [nrows][K] (lda=K).  B: hi/lo TRANSPOSED planes [64][ldb].
// Block: 256 thr / 4 waves; wave = 32 rows x 64 cols (2 col-tiles).
// Fragment layouts (verified m74/m101/m120-lineage):
//   A[m][k]: m=lane&31, k=(lane>>5)*8+j    B[k][n]: n=lane&31, same k
//   C/D: col=lane&31 (+32*ct), row=(reg&3)+8*(reg>>2)+4*(lane>>5)
// FLAGS bit0: add accbuf; bit1: gelu((v+bias)*0.25); bit2: also write split planes
// ---------------------------------------------------------------------------
template <int FLAGS>
__global__ __launch_bounds__(256, 4) void k_gemm_mx(
    const ushort_t* __restrict__ Ahi, const ushort_t* __restrict__ Alo,
    const ushort_t* __restrict__ Bhi, const ushort_t* __restrict__ Blo,
    int K, int ldb, int nrows,
    const float* __restrict__ accbuf, const float* __restrict__ bias,
    float* __restrict__ Cout, ushort_t* __restrict__ Chi, ushort_t* __restrict__ Clo)
{
    constexpr int KC = 32, LK = 40;          // LK shorts = 80 B row stride (16B-aligned, odd-ish bank rotation)
    __shared__ ushort_t sAh[128 * LK], sAl[128 * LK];
    __shared__ ushort_t sBh[64 * LK],  sBl[64 * LK];
    const int tid = threadIdx.x;
    const int w = tid >> 6, ln = tid & 63;
    const int l31 = ln & 31, hl = ln >> 5;
    const int rowbase = blockIdx.x * 128;

    floatx16 accv[2];
    #pragma unroll
    for (int ct = 0; ct < 2; ++ct)
        #pragma unroll
        for (int r = 0; r < 16; ++r) accv[ct][r] = 0.f;

    for (int kc = 0; kc < K; kc += KC) {
        __syncthreads();
        // stage A: 128 rows x 32 k (8-k groups), both planes, 16B copies
        #pragma unroll
        for (int i = 0; i < 2; ++i) {
            int f = tid + i * 256;           // 0..511
            int r = f >> 2, cg = f & 3;
            int row = rowbase + r;
            int so = r * LK + cg * 8;
            if (row < nrows) {
                size_t ga = (size_t)row * K + kc + cg * 8;
                *(uint4*)&sAh[so] = *(const uint4*)(Ahi + ga);
                *(uint4*)&sAl[so] = *(const uint4*)(Alo + ga);
            } else {
                *(uint4*)&sAh[so] = make_uint4(0, 0, 0, 0);
                *(uint4*)&sAl[so] = make_uint4(0, 0, 0, 0);
            }
        }
        // stage B: 64 n-rows x 32 k, both planes
        {
            int r = tid >> 2, cg = tid & 3;
            size_t gb = (size_t)r * ldb + kc + cg * 8;
            int so = r * LK + cg * 8;
            *(uint4*)&sBh[so] = *(const uint4*)(Bhi + gb);
            *(uint4*)&sBl[so] = *(const uint4*)(Blo + gb);
        }
        __syncthreads();
        const int arow = (w << 5) + l31;
        #pragma unroll
        for (int s = 0; s < 2; ++s) {
            const int koff = (s << 4) + (hl << 3);
            bf16x8 ah  = *(const bf16x8*)&sAh[arow * LK + koff];
            bf16x8 al  = *(const bf16x8*)&sAl[arow * LK + koff];
            bf16x8 bh0 = *(const bf16x8*)&sBh[l31 * LK + koff];
            bf16x8 bl0 = *(const bf16x8*)&sBl[l31 * LK + koff];
            bf16x8 bh1 = *(const bf16x8*)&sBh[(32 + l31) * LK + koff];
            bf16x8 bl1 = *(const bf16x8*)&sBl[(32 + l31) * LK + koff];
            accv[0] = __builtin_amdgcn_mfma_f32_32x32x16_bf16(ah, bh0, accv[0], 0, 0, 0);
            accv[1] = __builtin_amdgcn_mfma_f32_32x32x16_bf16(ah, bh1, accv[1], 0, 0, 0);
            accv[0] = __builtin_amdgcn_mfma_f32_32x32x16_bf16(al, bh0, accv[0], 0, 0, 0);
            accv[1] = __builtin_amdgcn_mfma_f32_32x32x16_bf16(al, bh1, accv[1], 0, 0, 0);
            accv[0] = __builtin_amdgcn_mfma_f32_32x32x16_bf16(ah, bl0, accv[0], 0, 0, 0);
            accv[1] = __builtin_amdgcn_mfma_f32_32x32x16_bf16(ah, bl1, accv[1], 0, 0, 0);
        }
    }
    // epilogue
    #pragma unroll
    for (int ct = 0; ct < 2; ++ct) {
        int col = (ct << 5) + l31;
        float bv = (FLAGS & 2) ? bias[col] : 0.f;
        #pragma unroll
        for (int r = 0; r < 16; ++r) {
            int row = rowbase + (w << 5) + (r & 3) + ((r >> 2) << 3) + (hl << 2);
            if (row < nrows) {
                size_t idx = (size_t)row * 64 + col;
                float v = accv[ct][r];
                if (FLAGS & 1) v += accbuf[idx];
                if (FLAGS & 2) v = gelu_exact((v + bv) * 0.25f);
                Cout[idx] = v;
                if (FLAGS & 4) {
                    ushort_t hh = f2bf(v);
                    Chi[idx] = hh;
                    Clo[idx] = f2bf(v - bf2f(hh));
                }
            }
        }
    }
}

// ---------------------------------------------------------------------------
// Feature epilogue: x = gelu(LN(y + lin_b)) + l2norm(emb); also split planes.
// ---------------------------------------------------------------------------
__global__ __launch_bounds__(256) void k_feat_post(
    const float* __restrict__ y, const float* __restrict__ lin_b,
    const float* __restrict__ ln_g, const float* __restrict__ ln_b,
    const float* __restrict__ emb, float* __restrict__ xout,
    ushort_t* __restrict__ xh, ushort_t* __restrict__ xl)
{
    int n = (blockIdx.x << 2) + (threadIdx.x >> 6);
    int c = threadIdx.x & 63;
    size_t base = (size_t)n * 64 + c;
    float v = y[base] + lin_b[c];
    float mean = wave_sum64(v) * 0.015625f;
    float t = v - mean;
    float var = wave_sum64(t * t) * 0.015625f;
    float vn = t * (1.0f / sqrtf(var + 1e-5f)) * ln_g[c] + ln_b[c];
    float g = gelu_exact(vn);
    float e = emb[base];
    float nrm = sqrtf(wave_sum64(e * e));
    float xv = g + e / fmaxf(nrm, 1e-12f);
    xout[base] = xv;
    ushort_t hh = f2bf(xv);
    xh[base] = hh;
    xl[base] = f2bf(xv - bf2f(hh));
}

// ---------------------------------------------------------------------------
// Edge aggregation -> split-bf16 z planes.  One wave per dst node, nt types.
// z[n][tt*256+h*64+d] = (sum_e p_e,h * x[src_e,d]) / S[n,h]
// ---------------------------------------------------------------------------
__global__ __launch_bounds__(256) void k_edge2(
    const float* __restrict__ x, const float* __restrict__ s_all,
    const int* __restrict__ row_ptr, const int* __restrict__ col,
    ushort_t* __restrict__ zh, ushort_t* __restrict__ zl, int t0, int nt)
{
    int n = (blockIdx.x << 2) + (threadIdx.x >> 6);   // grid = NN/4 exactly
    int lane = threadIdx.x & 63;
    int zrow = nt * 256;
    for (int tt = 0; tt < nt; ++tt) {
        int t = t0 + tt;
        int rp0 = row_ptr[t * (NN + 1) + n];
        int rp1 = row_ptr[t * (NN + 1) + n + 1];
        const int* colt = col + (size_t)t * EPN;      // per-type segment base
        const float4 sd = *(const float4*)&s_all[(size_t)n * 64 + t * 8 + 4];
        float z0 = 0.f, z1 = 0.f, z2 = 0.f, z3 = 0.f;
        float S0 = 0.f, S1 = 0.f, S2 = 0.f, S3 = 0.f;
        #pragma unroll 2
        for (int e = rp0; e < rp1; ++e) {
            int s = colt[e];                                  // wave-uniform
            const float4 ss = *(const float4*)&s_all[(size_t)s * 64 + t * 8];
            float l0 = ss.x + sd.x, l1 = ss.y + sd.y;
            float l2 = ss.z + sd.z, l3 = ss.w + sd.w;
            l0 = l0 > 0.f ? l0 : 0.2f * l0;
            l1 = l1 > 0.f ? l1 : 0.2f * l1;
            l2 = l2 > 0.f ? l2 : 0.2f * l2;
            l3 = l3 > 0.f ? l3 : 0.2f * l3;
            float p0 = __expf(l0), p1 = __expf(l1);
            float p2 = __expf(l2), p3 = __expf(l3);
            S0 += p0; S1 += p1; S2 += p2; S3 += p3;
            float xv = x[(size_t)s * 64 + lane];              // coalesced 256B
            z0 = fmaf(p0, xv, z0);
            z1 = fmaf(p1, xv, z1);
            z2 = fmaf(p2, xv, z2);
            z3 = fmaf(p3, xv, z3);
        }
        size_t zb = (size_t)n * zrow + tt * 256 + lane;
        float v0 = z0 / S0, v1 = z1 / S1, v2 = z2 / S2, v3 = z3 / S3;
        ushort_t h0 = f2bf(v0), h1 = f2bf(v1), h2 = f2bf(v2), h3 = f2bf(v3);
        zh[zb]       = h0;  zl[zb]       = f2bf(v0 - bf2f(h0));
        zh[zb + 64]  = h1;  zl[zb + 64]  = f2bf(v1 - bf2f(h1));
        zh[zb + 128] = h2;  zl[zb + 128] = f2bf(v2 - bf2f(h2));
        zh[zb + 192] = h3;  zl[zb + 192] = f2bf(v3 - bf2f(h3));
    }
}

// ---------------------------------------------------------------------------
extern "C" void kernel_launch(void* const* d_in, const int* in_sizes, int n_in,
                              void* d_out, int out_size, void* d_ws, size_t ws_size,
                              hipStream_t stream) {
    const float* fm    = (const float*)d_in[0];
    const float* emb   = (const float*)d_in[1];
    const float* lin_w = (const float*)d_in[2];
    const float* lin_b = (const float*)d_in[3];
    const float* ln_g  = (const float*)d_in[4];
    const float* ln_b  = (const float*)d_in[5];
    const float* Wsrc  = (const float*)d_in[6];
    const float* Wdst  = (const float*)d_in[7];
    const float* asrc  = (const float*)d_in[8];
    const float* adst  = (const float*)d_in[9];
    const float* cbias = (const float*)d_in[10];
    const int*   ei    = (const int*)d_in[11];
    float* out = (float*)d_out;
    (void)in_sizes; (void)n_in; (void)out_size;

    char* w = (char*)d_ws;
    size_t off = 0;
    auto alloc = [&](size_t bytes) -> void* {
        void* p = w + off;
        off += (bytes + 255) & ~(size_t)255;
        return p;
    };
    ushort_t* wcTh = (ushort_t*)alloc((size_t)LL * 64 * 64 * 2);
    ushort_t* wcTl = (ushort_t*)alloc((size_t)LL * 64 * 64 * 2);
    ushort_t* lwTh = (ushort_t*)alloc((size_t)64 * 256 * 2);
    ushort_t* lwTl = (ushort_t*)alloc((size_t)64 * 256 * 2);
    ushort_t* bpTh = (ushort_t*)alloc((size_t)LL * 64 * 1024 * 2);
    ushort_t* bpTl = (ushort_t*)alloc((size_t)LL * 64 * 1024 * 2);
    float* bsum    = (float*)alloc((size_t)LL * 64 * 4);
    int*   row_ptr = (int*)  alloc((size_t)TT * (NN + 1) * 4);
    int*   cursor  = (int*)  alloc((size_t)TT * NN * 4);
    int*   colarr  = (int*)  alloc((size_t)TT * EPN * 4);
    int*   csum    = (int*)  alloc((size_t)TT * NCH * 4);
    int*   cbase   = (int*)  alloc((size_t)TT * NCH * 4);
    float* x       = (float*)alloc(N64 * 4);
    ushort_t* xh   = (ushort_t*)alloc(N64 * 2);
    ushort_t* xl   = (ushort_t*)alloc(N64 * 2);
    float* s_all   = (float*)alloc(N64 * 4);
    float* accB    = (float*)alloc(N64 * 4);
    // big aliased region: fm split planes (pre-layer) / z split planes (layers)
    size_t rem = (ws_size > off) ? (ws_size - off) : 0;
    int NT = 1;
    if (rem >= (size_t)NN * 1024 * 4 + (8u << 20)) NT = 4;        // 409.6 MB
    else if (rem >= (size_t)NN * 512 * 4 + (8u << 20)) NT = 2;    // 204.8 MB
    size_t planeE = (size_t)NN * 256 * NT;                        // elems per z plane
    char* big = (char*)alloc(2 * planeE * 2 < 2 * (size_t)NN * 256 * 2
                             ? 2 * (size_t)NN * 256 * 2 : 2 * planeE * 2);
    ushort_t* fmh = (ushort_t*)big;
    ushort_t* fml = fmh + (size_t)NN * 256;
    ushort_t* zh  = (ushort_t*)big;
    ushort_t* zl  = zh + planeE;

    hipMemsetAsync(cursor, 0, (size_t)TT * NN * 4, stream);
    k_prep<<<512, 256, 0, stream>>>(Wsrc, Wdst, asrc, adst, cbias, lin_w,
                                    wcTh, wcTl, lwTh, lwTl, bpTh, bpTl, bsum);
    k_hist<<<(TT * EE + 255) / 256, 256, 0, stream>>>(ei, cursor);
    k_scan1<<<TT * NCH, 256, 0, stream>>>(cursor, csum);
    k_scan2<<<1, 64, 0, stream>>>(csum, cbase, row_ptr);
    k_scan3<<<TT * NCH, 256, 0, stream>>>(cursor, cbase, row_ptr);
    k_scatter<<<(TT * EPN + 255) / 256, 256, 0, stream>>>(ei, cursor, colarr);

    const int GB = (NN + 127) / 128;   // 782 blocks (128 rows each)
    // feature transform: split fm -> GEMM K=256 -> LN/gelu/emb epilogue
    k_split<<<(NN * 64 + 255) / 256, 256, 0, stream>>>(fm, fmh, fml, NN * 64);
    k_gemm_mx<0><<<GB, 256, 0, stream>>>(fmh, fml, lwTh, lwTl, 256, 256, NN,
                                         nullptr, nullptr, accB, nullptr, nullptr);
    k_feat_post<<<NN / 4, 256, 0, stream>>>(accB, lin_b, ln_g, ln_b, emb, x, xh, xl);

    const int nb = TT / NT;
    for (int l = 0; l < LL; ++l) {
        // collapsed attention-logit projection: s_all = x @ wcoll_l  [N,64]
        k_gemm_mx<0><<<GB, 256, 0, stream>>>(xh, xl, wcTh + l * 4096, wcTl + l * 4096,
                                             64, 64, NN, nullptr, nullptr,
                                             s_all, nullptr, nullptr);
        float* dest = (l == 0) ? x : out;
        const ushort_t* Bh = bpTh + (size_t)l * 65536;
        const ushort_t* Bl = bpTl + (size_t)l * 65536;
        for (int b = 0; b < nb; ++b) {
            k_edge2<<<NN / 4, 256, 0, stream>>>(x, s_all, row_ptr, colarr,
                                                zh, zl, b * NT, NT);
            int K = NT * 256;
            const ushort_t* Bhb = Bh + b * K;   // k-offset within ldb=1024 rows
            const ushort_t* Blb = Bl + b * K;
            bool last = (b == nb - 1);
            if (!last) {
                if (b == 0)
                    k_gemm_mx<0><<<GB, 256, 0, stream>>>(zh, zl, Bhb, Blb, K, 1024, NN,
                                                         nullptr, nullptr, accB,
                                                         nullptr, nullptr);
                else
                    k_gemm_mx<1><<<GB, 256, 0, stream>>>(zh, zl, Bhb, Blb, K, 1024, NN,
                                                         accB, nullptr, accB,
                                                         nullptr, nullptr);
            } else {
                // final chunk: (+accB if nb>1) + gelu((v+bias)/4); layer0 also
                // refreshes x split planes for the next layer's GEMMs
                if (nb == 1) {
                    if (l == 0)
                        k_gemm_mx<6><<<GB, 256, 0, stream>>>(zh, zl, Bhb, Blb, K, 1024,
                                                             NN, nullptr, bsum + l * 64,
                                                             dest, xh, xl);
                    else
                        k_gemm_mx<2><<<GB, 256, 0, stream>>>(zh, zl, Bhb, Blb, K, 1024,
                                                             NN, nullptr, bsum + l * 64,
                                                             dest, nullptr, nullptr);
                } else {
                    if (l == 0)
                        k_gemm_mx<7><<<GB, 256, 0, stream>>>(zh, zl, Bhb, Blb, K, 1024,
                                                             NN, accB, bsum + l * 64,
                                                             dest, xh, xl);
                    else
                        k_gemm_mx<3><<<GB, 256, 0, stream>>>(zh, zl, Bhb, Blb, K, 1024,
                                                             NN, accB, bsum + l * 64,
                                                             dest, nullptr, nullptr);
                }
            }
        }
    }
}